// Round 3
// baseline (125.660 us; speedup 1.0000x reference)
//
#include <hip/hip_runtime.h>
#include <hip/hip_bf16.h>

typedef __attribute__((ext_vector_type(8))) short short8;
typedef __attribute__((ext_vector_type(4))) float f32x4;

#define LDST 72   // bf16 elements per LDS row (144B, 16B-aligned, bank-friendly)
#define MFMA16(a, b, c) __builtin_amdgcn_mfma_f32_16x16x32_bf16(a, b, c, 0, 0, 0)

__device__ __forceinline__ float bf2f(unsigned short h) {
  return __uint_as_float(((unsigned)h) << 16);
}

// One block = one (batch, window). 256 threads = 4 waves; wave w owns output
// rows m0 = w*16 .. +15. Roll(-32) folded into global row index: window row i
// <-> global row p=(n*64+32+i)&8191 for loads and the x store.
//
// Accuracy plan: Q,K split hi/lo by truncation (3-term MFMA QK^T, ~2^-15 rel);
// V single bf16 (biased-RNE, ~2^-9): adds ~5e-3 to x vs the 4.6e-2 threshold.
// LDS 37.4KB -> 4 blocks/CU.
__global__ __launch_bounds__(256, 4)
void swin64_attn(const float* __restrict__ qg, const float* __restrict__ kg,
                 const float* __restrict__ vg, const float* __restrict__ tbl,
                 float* __restrict__ ox, float* __restrict__ oa) {
  __shared__ unsigned short Khi[64 * LDST], Klo[64 * LDST];
  __shared__ unsigned short Vhi[64 * LDST];      // transposed [c][j], XOR-swizzled
  __shared__ unsigned short Pb[64 * LDST];
  __shared__ float btab[128];

  const int t = threadIdx.x;
  const int b = blockIdx.x >> 7;
  const int n = blockIdx.x & 127;
  const int l = t & 63;
  const int w = t >> 6;
  const int r15 = l & 15;
  const int g4 = l >> 4;
  const int m0 = w * 16;

  // ---- issue Q loads first (wave-private rows -> registers, no LDS)
  const int qrow = (n * 64 + 32 + m0 + r15) & 8191;
  const float* qp = qg + ((size_t)b * 8192 + (size_t)qrow) * 64;
  const float4 qa0 = *(const float4*)(qp + g4 * 8);
  const float4 qa1 = *(const float4*)(qp + g4 * 8 + 4);
  const float4 qa2 = *(const float4*)(qp + 32 + g4 * 8);
  const float4 qa3 = *(const float4*)(qp + 32 + g4 * 8 + 4);

  if (t < 127) btab[t] = tbl[t];

  // ---- stage K (hi/lo trunc split, packed u32 writes) and V (bf16, transposed)
#pragma unroll
  for (int s = 0; s < 2; ++s) {
    const int seg = t + s * 256;      // 0..511: 64 rows x 8 col-octets
    const int row = seg >> 3;
    const int c8 = seg & 7;
    const int p = (n * 64 + 32 + row) & 8191;
    const size_t g = ((size_t)b * 8192 + (size_t)p) * 64 + (size_t)(c8 * 8);

    {
      const float4 a0 = *(const float4*)(kg + g);
      const float4 a1 = *(const float4*)(kg + g + 4);
      const float f[8] = {a0.x, a0.y, a0.z, a0.w, a1.x, a1.y, a1.z, a1.w};
      unsigned uh[4], ul[4];
#pragma unroll
      for (int i = 0; i < 4; ++i) {
        const unsigned u0 = __float_as_uint(f[2 * i]);
        const unsigned u1 = __float_as_uint(f[2 * i + 1]);
        const float r0 = f[2 * i]     - __uint_as_float(u0 & 0xFFFF0000u);
        const float r1 = f[2 * i + 1] - __uint_as_float(u1 & 0xFFFF0000u);
        uh[i] = (u0 >> 16) | (u1 & 0xFFFF0000u);
        ul[i] = (__float_as_uint(r0) >> 16) | (__float_as_uint(r1) & 0xFFFF0000u);
      }
      *(uint4*)&Khi[row * LDST + c8 * 8] = make_uint4(uh[0], uh[1], uh[2], uh[3]);
      *(uint4*)&Klo[row * LDST + c8 * 8] = make_uint4(ul[0], ul[1], ul[2], ul[3]);
    }
    {
      const float4 a0 = *(const float4*)(vg + g);
      const float4 a1 = *(const float4*)(vg + g + 4);
      const float f[8] = {a0.x, a0.y, a0.z, a0.w, a1.x, a1.y, a1.z, a1.w};
#pragma unroll
      for (int i = 0; i < 8; ++i) {
        const int c = c8 * 8 + i;          // channel -> Vt row
        // j stored at 8-block (j>>3) ^ ((c>>3)&7): keeps frag contiguity,
        // spreads scatter-write banks.
        const int idx = c * LDST + ((((row >> 3) ^ ((c >> 3) & 7)) << 3) | (row & 7));
        Vhi[idx] = (unsigned short)((__float_as_uint(f[i]) + 0x8000u) >> 16);
      }
    }
  }

  // ---- Q hi/lo trunc split into register fragments
  short8 qh0, qh1, ql0, ql1;
  {
    const float f0[8] = {qa0.x, qa0.y, qa0.z, qa0.w, qa1.x, qa1.y, qa1.z, qa1.w};
    const float f1[8] = {qa2.x, qa2.y, qa2.z, qa2.w, qa3.x, qa3.y, qa3.z, qa3.w};
#pragma unroll
    for (int i = 0; i < 8; ++i) {
      const unsigned u0 = __float_as_uint(f0[i]);
      qh0[i] = (short)(u0 >> 16);
      ql0[i] = (short)(__float_as_uint(f0[i] - __uint_as_float(u0 & 0xFFFF0000u)) >> 16);
      const unsigned u1 = __float_as_uint(f1[i]);
      qh1[i] = (short)(u1 >> 16);
      ql1[i] = (short)(__float_as_uint(f1[i] - __uint_as_float(u1 & 0xFFFF0000u)) >> 16);
    }
  }
  __syncthreads();

  // fragment loaders: lane l -> row (rb + l&15), 8 contiguous k at kb*32+(l>>4)*8
  auto ldf = [&](const unsigned short* a, int rb, int kb) -> short8 {
    return *(const short8*)&a[(rb + r15) * LDST + kb * 32 + g4 * 8];
  };
  auto ldv = [&](const unsigned short* a, int rb, int kb) -> short8 {
    const int c = rb + r15;
    const int blk = (kb * 4 + g4) ^ ((c >> 3) & 7);
    return *(const short8*)&a[c * LDST + blk * 8];
  };

  // ---- QK^T with hi/lo split (drop lo*lo)
  f32x4 acc[4];
#pragma unroll
  for (int nt = 0; nt < 4; ++nt) {
    const short8 kh0 = ldf(Khi, nt * 16, 0), kh1 = ldf(Khi, nt * 16, 1);
    const short8 kl0 = ldf(Klo, nt * 16, 0), kl1 = ldf(Klo, nt * 16, 1);
    f32x4 a = {0.f, 0.f, 0.f, 0.f};
    a = MFMA16(qh0, kh0, a);
    a = MFMA16(qh1, kh1, a);
    a = MFMA16(ql0, kh0, a);
    a = MFMA16(ql1, kh1, a);
    a = MFMA16(qh0, kl0, a);
    a = MFMA16(qh1, kl1, a);
    acc[nt] = a;
  }

  // ---- scale + bias + shift-mask; D layout: row = m0 + g4*4 + r, col = nt*16 + r15
  float sv[4][4];  // [nt][r]
#pragma unroll
  for (int nt = 0; nt < 4; ++nt) {
#pragma unroll
    for (int r = 0; r < 4; ++r) {
      const int i = m0 + g4 * 4 + r;
      const int j = nt * 16 + r15;
      float sx = acc[nt][r] * 0.125f + btab[i - j + 63];
      if (n == 127 && ((i < 32) != (j < 32))) sx -= 100.f;
      sv[nt][r] = sx;
    }
  }

  // ---- row softmax: reduce over 16 lanes of the row-group (masks 1,2,4,8)
  float mx[4], rinv[4], pr[4][4];
#pragma unroll
  for (int r = 0; r < 4; ++r) {
    float m2 = fmaxf(fmaxf(sv[0][r], sv[1][r]), fmaxf(sv[2][r], sv[3][r]));
    m2 = fmaxf(m2, __shfl_xor(m2, 1));
    m2 = fmaxf(m2, __shfl_xor(m2, 2));
    m2 = fmaxf(m2, __shfl_xor(m2, 4));
    m2 = fmaxf(m2, __shfl_xor(m2, 8));
    mx[r] = m2;
  }
#pragma unroll
  for (int nt = 0; nt < 4; ++nt) {
#pragma unroll
    for (int r = 0; r < 4; ++r) pr[nt][r] = __expf(sv[nt][r] - mx[r]);
  }
#pragma unroll
  for (int r = 0; r < 4; ++r) {
    float s2 = pr[0][r] + pr[1][r] + pr[2][r] + pr[3][r];
    s2 += __shfl_xor(s2, 1);
    s2 += __shfl_xor(s2, 2);
    s2 += __shfl_xor(s2, 4);
    s2 += __shfl_xor(s2, 8);
    rinv[r] = 1.f / s2;
  }

  // ---- write attn (normalized, f32) + unnormalized bf16 P into dedicated LDS
  float* ap = oa + (size_t)blockIdx.x * 4096;
#pragma unroll
  for (int nt = 0; nt < 4; ++nt) {
#pragma unroll
    for (int r = 0; r < 4; ++r) {
      const int i = m0 + g4 * 4 + r;
      const int j = nt * 16 + r15;
      Pb[i * LDST + j] = (unsigned short)((__float_as_uint(pr[nt][r]) + 0x8000u) >> 16);
      ap[i * 64 + j] = pr[nt][r] * rinv[r];
    }
  }
  __syncthreads();   // hard fence between P writes and P fragment reads

  // ---- PV: x = P * Vhi, scale rows by 1/sum at the end
  const short8 pa0 = ldf(Pb, m0, 0), pa1 = ldf(Pb, m0, 1);
#pragma unroll
  for (int ct = 0; ct < 4; ++ct) {
    const short8 vh0 = ldv(Vhi, ct * 16, 0), vh1 = ldv(Vhi, ct * 16, 1);
    f32x4 a = {0.f, 0.f, 0.f, 0.f};
    a = MFMA16(pa0, vh0, a);
    a = MFMA16(pa1, vh1, a);
#pragma unroll
    for (int r = 0; r < 4; ++r) {
      const int i = m0 + g4 * 4 + r;
      const int p2 = (n * 64 + 32 + i) & 8191;
      ox[((size_t)b * 8192 + (size_t)p2) * 64 + ct * 16 + r15] = a[r] * rinv[r];
    }
  }
}

extern "C" void kernel_launch(void* const* d_in, const int* in_sizes, int n_in,
                              void* d_out, int out_size, void* d_ws, size_t ws_size,
                              hipStream_t stream) {
  const float* q = (const float*)d_in[0];
  const float* k = (const float*)d_in[1];
  const float* v = (const float*)d_in[2];
  const float* tbl = (const float*)d_in[3];
  float* ox = (float*)d_out;
  float* oa = ox + (size_t)64 * 8192 * 64;  // x first, then attn
  swin64_attn<<<dim3(8192), dim3(256), 0, stream>>>(q, k, v, tbl, ox, oa);
}